// Round 8
// baseline (855.826 us; speedup 1.0000x reference)
//
#include <hip/hip_runtime.h>
#include <cstddef>
#include <cstdint>

// ---------------- constants ----------------
#define NB    2
#define NP    1024    // patches per image
#define DFEAT 256
#define DSTATE 16
#define NEDGE 1984    // grid edges: 31*63 + 31

typedef unsigned short ushortb;

// MFMA fragment types (gfx950 32x32x16 bf16)
typedef float fx16 __attribute__((ext_vector_type(16)));
typedef short s16x8 __attribute__((ext_vector_type(8)));

// ---------------- helpers ----------------
__device__ __forceinline__ float bf2f(unsigned short u){
  union { unsigned int i; float f; } c; c.i = ((unsigned int)u) << 16; return c.f;
}
__device__ __forceinline__ unsigned short f2bf(float f){
  union { float f; unsigned int i; } c; c.f = f;
  unsigned int u = c.i;
  unsigned int r = (u + 0x7fffu + ((u >> 16) & 1u)) >> 16;
  return (unsigned short)r;
}
// dtype-generic input load: isbf ? bf16[i] : fp32[i]
__device__ __forceinline__ float ldin(const void* p, size_t i, int isbf){
  return isbf ? bf2f(((const ushortb*)p)[i]) : ((const float*)p)[i];
}
__device__ __forceinline__ float gelu_f(float x){
  return 0.5f * x * (1.0f + erff(x * 0.70710678118654752f));
}
__device__ __forceinline__ unsigned int f2sort(float f){
  union { float f; unsigned int i; } c; c.f = f;
  return (c.i & 0x80000000u) ? ~c.i : (c.i | 0x80000000u);
}

// ---------------- ws layout (float element offsets) ----------------
constexpr size_t AL(size_t x){ return (x + 63) & ~(size_t)63; }
constexpr size_t O_W1    = 0;                       // 1728  conv1 w fp32
constexpr size_t O_B1    = AL(O_W1 + 1728);         // 64
constexpr size_t O_W2    = AL(O_B1 + 64);           // 73728 floats = 147456 bf16, FRAGMENT-MAJOR
                                                    //   sg = c*18 + tap*2 + ksub (c = 32-ic chunk)
constexpr size_t O_B2    = AL(O_W2 + 73728);        // 128
constexpr size_t O_FCW   = AL(O_B2 + 128);          // 32768 [df][128]
constexpr size_t O_FCB   = AL(O_FCW + 32768);       // 256
constexpr size_t O_WDW   = AL(O_FCB + 256);         // 65536 TRANSPOSED [k][df]
constexpr size_t O_WDB   = AL(O_WDW + 65536);       // 256
constexpr size_t O_BWO   = AL(O_WDB + 256);         // 4096 TRANSPOSED [k][s]
constexpr size_t O_BBO   = AL(O_BWO + 4096);        // 16
constexpr size_t O_CWO   = AL(O_BBO + 16);          // 4096 TRANSPOSED [k][s]
constexpr size_t O_CBO   = AL(O_CWO + 4096);        // 16
constexpr size_t O_OW    = AL(O_CBO + 16);          // 65536 TRANSPOSED [k][df]
constexpr size_t O_OB    = AL(O_OW + 65536);        // 256
constexpr size_t O_AF    = AL(O_OB + 256);          // 4096  A = -exp(A_log), [f][s]
constexpr size_t O_DD    = AL(O_AF + 4096);         // 256
constexpr size_t O_LNG   = AL(O_DD + 256);          // 256
constexpr size_t O_LNB   = AL(O_LNG + 256);         // 256
constexpr size_t O_FEATS = AL(O_LNB + 256);         // 2*1024*256
constexpr size_t O_GPROJ = AL(O_FEATS + (size_t)NB*NP*DFEAT); // 512
constexpr size_t O_GPRIM = AL(O_GPROJ + NB*DFEAT);  // 512
constexpr size_t O_RSEM  = AL(O_GPRIM + NB*DFEAT);  // 2048
constexpr size_t O_BFS   = AL(O_RSEM + NB*NP);      // 2048 (int)
constexpr size_t O_PAR   = AL(O_BFS + NB*NP);       // 2048 (int)
constexpr size_t O_X     = AL(O_PAR + NB*NP);       // 2*1024*256 RASTER (node) order
constexpr size_t O_DELTA = AL(O_X + (size_t)NB*NP*DFEAT);     // RASTER order
constexpr size_t O_BP    = AL(O_DELTA + (size_t)NB*NP*DFEAT); // 2*1024*16 RASTER
constexpr size_t O_CP    = AL(O_BP + NB*NP*DSTATE);           // RASTER
constexpr size_t O_YR    = AL(O_CP + NB*NP*DSTATE); // 2*1024*256
constexpr size_t O_FLAG  = AL(O_YR + (size_t)NB*NP*DFEAT);    // 1 int: is-bf16 flag
constexpr size_t O_LVL   = AL(O_FLAG + 64);         // NB*1040 ints: [nlvl, loff[0..nlvl]]

// ---------------- K-1: sniff input dtype (bf16 vs fp32) from images buffer -----------
__global__ __launch_bounds__(256) void k_sniff(const void* img, float* ws)
{
  __shared__ int cnt;
  int tid = threadIdx.x;
  if (tid == 0) cnt = 0;
  __syncthreads();
  const ushortb* u = (const ushortb*)img;
  int local = 0;
  for (int k = 0; k < 16; k++){
    unsigned short v = u[tid * 16 + k];
    if (v == 0 || v == 0x8000u){ local++; continue; }
    float f = fabsf(bf2f(v));
    if (f >= 1e-8f && f <= 64.f) local++;    // plausible N(0,1) bf16
  }
  atomicAdd(&cnt, local);
  __syncthreads();
  if (tid == 0) ((int*)(ws + O_FLAG))[0] = (cnt >= 3900) ? 1 : 0;  // >=95% plausible
}

// ---------------- K0: convert weights + zero YR + g_proj/g_prime (all fused) ---------
// blocks [0,990): weight convert; [990,3038): YR zero; [3038,3294): gmm rows.
__global__ __launch_bounds__(256) void k_convert(const void* c1w, const void* c1b, const void* c2w,
                          const void* c2b, const void* fcw, const void* fcb,
                          const void* alog, const void* dvec,
                          const void* bw, const void* bb, const void* cw, const void* cb,
                          const void* wdw, const void* wdb,
                          const void* ow, const void* ob,
                          const void* lng, const void* lnb,
                          const void* lang, const void* wgate, const void* wgp,
                          float* ws)
{
  const int F = ((const int*)(ws + O_FLAG))[0];
  if (blockIdx.x >= 3038){  // gmm branch: wave-per-row coalesced dual GEMV
    int row = (blockIdx.x - 3038) * 4 + (threadIdx.x >> 6);
    int lane = threadIdx.x & 63;
    int mat = row >> 9;
    int b   = (row >> 8) & 1;
    int df  = row & 255;
    const void* W = mat ? wgp : wgate;
    float s = 0.f;
    for (int k = lane; k < 896; k += 64)
      s += ldin(lang, (size_t)b * 896 + k, F) * ldin(W, (size_t)df * 896 + k, F);
    s += __shfl_xor(s, 1);  s += __shfl_xor(s, 2);  s += __shfl_xor(s, 4);
    s += __shfl_xor(s, 8);  s += __shfl_xor(s, 16); s += __shfl_xor(s, 32);
    if (lane == 0) ws[(mat ? O_GPRIM : O_GPROJ) + b * 256 + df] = s;
    return;
  }
  if (blockIdx.x >= 990){   // init branch: zero YR
    size_t i2 = (size_t)(blockIdx.x - 990) * 256 + threadIdx.x;
    if (i2 < (size_t)NB * NP * DFEAT) ws[O_YR + i2] = 0.f;
    return;
  }
  int i = blockIdx.x * 256 + threadIdx.x;
  if (i < 1728){ ws[O_W1 + i] = ldin(c1w, i, F); return; } i -= 1728;
  if (i < 64){ ws[O_B1 + i] = ldin(c1b, i, F); return; } i -= 64;
  if (i < 73728){
    // fragment-major bf16-split conv2 weights for 32x32x16 MFMA.
    // sg = c*18 + tap*2 + ksub (c = 32-ic chunk); lane ln holds oc = nt*32+(ln&31),
    // ic = c*32 + ksub*16 + (ln>>5)*8 + e.
    int sg = i >> 11;           // 0..35
    int r = i & 2047;
    int nt = r >> 9;
    int r2 = r & 511;           // ln*8 + e
    int ln = r2 >> 3, e = r2 & 7;
    int c  = sg / 18, s = sg - c * 18;
    int tap = s >> 1, ksub = s & 1;
    int oc = nt * 32 + (ln & 31);
    int ic = c * 32 + ksub * 16 + (ln >> 5) * 8 + e;
    float v = ldin(c2w, (size_t)(oc * 64 + ic) * 9 + tap, F);
    ushortb hi = f2bf(v);
    float lo = v - bf2f(hi);
    ushortb* WB = (ushortb*)(ws + O_W2);
    size_t cb = ((size_t)(sg * 4 + nt)) * 2;
    WB[cb * 512 + r2]       = hi;         // plane 0
    WB[(cb + 1) * 512 + r2] = f2bf(lo);   // plane 1
    return;
  } i -= 73728;
  if (i < 128){ ws[O_B2 + i] = ldin(c2b, i, F); return; } i -= 128;
  if (i < 32768){ ws[O_FCW + i] = ldin(fcw, i, F); return; } i -= 32768;
  if (i < 256){ ws[O_FCB + i] = ldin(fcb, i, F); return; } i -= 256;
  if (i < 65536){  // WDW transposed: dst[k*256+df] = src[df*256+k]
    int k = i >> 8, df = i & 255;
    ws[O_WDW + i] = ldin(wdw, (size_t)df * 256 + k, F); return;
  } i -= 65536;
  if (i < 256){ ws[O_WDB + i] = ldin(wdb, i, F); return; } i -= 256;
  if (i < 4096){   // B_w transposed: dst[k*16+s] = src[s*256+k]
    int k = i >> 4, s = i & 15;
    ws[O_BWO + i] = ldin(bw, (size_t)s * 256 + k, F); return;
  } i -= 4096;
  if (i < 16){ ws[O_BBO + i] = ldin(bb, i, F); return; } i -= 16;
  if (i < 4096){   // C_w transposed
    int k = i >> 4, s = i & 15;
    ws[O_CWO + i] = ldin(cw, (size_t)s * 256 + k, F); return;
  } i -= 4096;
  if (i < 16){ ws[O_CBO + i] = ldin(cb, i, F); return; } i -= 16;
  if (i < 65536){  // out_w transposed: dst[k*256+df] = src[df*256+k]
    int k = i >> 8, df = i & 255;
    ws[O_OW + i] = ldin(ow, (size_t)df * 256 + k, F); return;
  } i -= 65536;
  if (i < 256){ ws[O_OB + i] = ldin(ob, i, F); return; } i -= 256;
  if (i < 4096){ ws[O_AF + i] = -expf(ldin(alog, i, F)); return; } i -= 4096;
  if (i < 256){ ws[O_DD + i] = ldin(dvec, i, F); return; } i -= 256;
  if (i < 256){ ws[O_LNG + i] = ldin(lng, i, F); return; } i -= 256;
  if (i < 256){ ws[O_LNB + i] = ldin(lnb, i, F); }
}

// ---------------- K1: per-patch conv1 + MFMA conv2 (bf16 3-split, M-halves) ----------
// R8: M-half decomposition kills R7's conv1 doubling. Per half (8 px rows): conv1
// computes 9 image rows (1 halo row shared -> 1.125x conv1 total) into a
// [10][18][64ic] zero-padded A tile (hi+lo = 45 KB; BOTH ic-chunks resident ->
// one 36-step full-K MFMA loop, half the barriers of R7). Waves: (mt 0..3, ng 0..1)
// = 1 M-tile x 2 N-tiles -> acc 32 regs + frags 24 -> no spill at the 128-reg cap,
// 2 blocks/CU (LDS ~51 KB). Swizzle slot^=(gc&7): 8 accesses/bank (b128 floor).
__global__ __launch_bounds__(512, 4) void k_patch(const void* __restrict__ img,
                                                  const float* __restrict__ ws,
                                                  float* __restrict__ feats)
{
  __shared__ __align__(16) ushortb Abuf[2 * 11520];  // hi [0], lo [11520]: [10][18][64]
  __shared__ float timg[768];      // [3 c][256 px]
  __shared__ float pool8[512];     // [wv][2 nt local][32 oc]
  __shared__ float pm[128];        // pooled mean
  const int F = ((const int*)(ws + O_FLAG))[0];
  const float* W1 = ws + O_W1;  const float* B1 = ws + O_B1;
  const float* FCW = ws + O_FCW; const float* FCB = ws + O_FCB;
  const s16x8* BF = (const s16x8*)(ws + O_W2);   // fragment-major B

  int blk = blockIdx.x; int b = blk >> 10; int pidx = blk & 1023;
  int ph = pidx >> 5, pw = pidx & 31;
  int tid = threadIdx.x;
  uint4 z4 = make_uint4(0u, 0u, 0u, 0u);

  // stage input tile (16x16x3) into LDS
  if (tid < 256){
    int y = tid >> 4, x = tid & 15;
    #pragma unroll
    for (int c = 0; c < 3; c++)
      timg[c * 256 + tid] =
        ldin(img, (((size_t)b * 3 + c) * 512 + (ph * 16 + y)) * 512 + (pw * 16 + x), F);
  }
  // zero column pads (gc = 0, 17) for all 10 rows, both planes (never overwritten)
  for (int z = tid; z < 320; z += 512){
    int plane = z / 160; int z2 = z - plane * 160;   // 160 = 10 rows * 2 cols * 8 q
    int cell = z2 >> 3, q = z2 & 7;
    int lr = cell >> 1; int gc = (cell & 1) ? 17 : 0;
    *(uint4*)&Abuf[plane * 11520 + ((lr * 18 + gc) << 6) + (q << 3)] = z4;
  }
  __syncthreads();

  int wv = tid >> 6, ln = tid & 63;
  int l31 = ln & 31, lhi = ln >> 5;
  int xcol = ln & 15, yrow = l31 >> 4;
  int mt = wv >> 1, ng = wv & 1;

  float psum0 = 0.f, psum1 = 0.f;   // pooled partials (lane-local, across halves)

  for (int h = 0; h < 2; h++){
    // zero this half's pad row (lr = h?9:0, gc 1..16, both planes)
    {
      int pr = h ? 9 : 0;
      for (int z = tid; z < 256; z += 512){
        int plane = z >> 7; int z2 = z & 127;
        int gc = 1 + (z2 >> 3); int q = z2 & 7;
        *(uint4*)&Abuf[plane * 11520 + ((pr * 18 + gc) << 6) + (q << 3)] = z4;
      }
    }
    // conv1: 9 image rows (h ? 7..15 : 0..8); 1152 units of (px 0..143, 8-oc group)
    for (int u = tid; u < 1152; u += 512){
      int og = u / 144; int px = u - og * 144;
      int r9 = px >> 4, col = px & 15;
      int ir = h ? (7 + r9) : r9;
      float pin[27];
      #pragma unroll
      for (int cc = 0; cc < 3; cc++)
        #pragma unroll
        for (int dy = 0; dy < 3; dy++)
          #pragma unroll
          for (int dx = 0; dx < 3; dx++){
            int y = ir + dy - 1, x = col + dx - 1;
            bool ok = (y >= 0 && y < 16 && x >= 0 && x < 16);
            pin[cc * 9 + dy * 3 + dx] = ok ? timg[cc * 256 + y * 16 + x] : 0.f;
          }
      int oc0 = og * 8;
      float av[8];
      #pragma unroll
      for (int o = 0; o < 8; o++){
        float a = B1[oc0 + o];
        #pragma unroll
        for (int t = 0; t < 27; t++) a += W1[(oc0 + o) * 27 + t] * pin[t];
        av[o] = gelu_f(a);
      }
      unsigned int hp[4], lp[4];
      #pragma unroll
      for (int q = 0; q < 4; q++){
        float v0 = av[2 * q], v1 = av[2 * q + 1];
        ushortb h0 = f2bf(v0), h1 = f2bf(v1);
        float l0 = v0 - bf2f(h0), l1 = v1 - bf2f(h1);
        hp[q] = (unsigned int)h0 | ((unsigned int)h1 << 16);
        lp[q] = (unsigned int)f2bf(l0) | ((unsigned int)f2bf(l1) << 16);
      }
      int lr = h ? r9 : (r9 + 1);
      int gc = col + 1;
      int idx = ((lr * 18 + gc) << 6) + ((og ^ (gc & 7)) << 3);
      *(uint4*)&Abuf[idx] = make_uint4(hp[0], hp[1], hp[2], hp[3]);
      *(uint4*)&Abuf[11520 + idx] = make_uint4(lp[0], lp[1], lp[2], lp[3]);
    }
    __syncthreads();

    // MFMA: full K = 576 in 36 steps (tap 0..8 x icsub 0..3)
    fx16 acc0, acc1;
    #pragma unroll
    for (int r = 0; r < 16; r++){ acc0[r] = 0.f; acc1[r] = 0.f; }
    for (int s = 0; s < 36; s++){
      int tap = s >> 2, icsub = s & 3;
      int dyq = tap / 3, dxq = tap - dyq * 3;
      int lr = 2 * mt + yrow + dyq;           // local padded row 0..9
      int gc = xcol + dxq;                    // padded col 0..17
      int slot = (icsub << 1) + lhi;          // 8-ic slot 0..7
      int iA = ((lr * 18 + gc) << 6) + ((slot ^ (gc & 7)) << 3);
      s16x8 fa_h = *(const s16x8*)&Abuf[iA];
      s16x8 fa_l = *(const s16x8*)&Abuf[11520 + iA];
      int sg = (icsub >> 1) * 18 + (tap << 1) + (icsub & 1);
      const s16x8* bq = BF + (size_t)(((sg * 4 + ng * 2) * 2) * 64 + ln);
      s16x8 fb0h = bq[0];
      s16x8 fb0l = bq[64];
      s16x8 fb1h = bq[128];
      s16x8 fb1l = bq[192];
      acc0 = __builtin_amdgcn_mfma_f32_32x32x16_bf16(fa_h, fb0h, acc0, 0, 0, 0);
      acc1 = __builtin_amdgcn_mfma_f32_32x32x16_bf16(fa_h, fb1h, acc1, 0, 0, 0);
      acc0 = __builtin_amdgcn_mfma_f32_32x32x16_bf16(fa_l, fb0h, acc0, 0, 0, 0);
      acc1 = __builtin_amdgcn_mfma_f32_32x32x16_bf16(fa_l, fb1h, acc1, 0, 0, 0);
      acc0 = __builtin_amdgcn_mfma_f32_32x32x16_bf16(fa_h, fb0l, acc0, 0, 0, 0);
      acc1 = __builtin_amdgcn_mfma_f32_32x32x16_bf16(fa_h, fb1l, acc1, 0, 0, 0);
    }
    // pool this half's output (bias + gelu), accumulate lane-local
    {
      float bz0 = ws[O_B2 + (ng * 2) * 32 + l31];
      float bz1 = ws[O_B2 + (ng * 2 + 1) * 32 + l31];
      float s0 = 0.f, s1 = 0.f;
      #pragma unroll
      for (int r = 0; r < 16; r++){
        s0 += gelu_f(acc0[r] + bz0);
        s1 += gelu_f(acc1[r] + bz1);
      }
      psum0 += s0; psum1 += s1;
    }
    __syncthreads();   // A dead before next half's conv1 overwrites it
  }

  // fold k-half lanes, write per-wave pool partials: pool8[wv][n][32]
  {
    float s0 = psum0 + __shfl_xor(psum0, 32);
    float s1 = psum1 + __shfl_xor(psum1, 32);
    if (lhi == 0){
      pool8[wv * 64 + l31] = s0;
      pool8[wv * 64 + 32 + l31] = s1;
    }
  }
  __syncthreads();
  if (tid < 128){
    int oc = tid; int nt = oc >> 5; int ngo = nt >> 1; int n = nt & 1; int l = oc & 31;
    float sv = pool8[(0 * 2 + ngo) * 64 + n * 32 + l]
             + pool8[(1 * 2 + ngo) * 64 + n * 32 + l]
             + pool8[(2 * 2 + ngo) * 64 + n * 32 + l]
             + pool8[(3 * 2 + ngo) * 64 + n * 32 + l];
    pm[oc] = sv * (1.f / 256.f);
  }
  __syncthreads();

  // fc 128 -> 256 (threads 0..255)
  if (tid < 256){
    int df = tid;
    float s = FCB[df];
    const float* wrow = FCW + (size_t)df * 128;
    #pragma unroll
    for (int k = 0; k < 128; k += 4)
      s += wrow[k] * pm[k] + wrow[k + 1] * pm[k + 1]
         + wrow[k + 2] * pm[k + 2] + wrow[k + 3] * pm[k + 3];
    feats[((size_t)(b * 1024 + pidx)) * 256 + df] = s;
  }
}

// ---------------- K3: FUSED structure + raster xdelta --------------------------------
// blocks 0,1: MST+BFS (per batch). blocks 2..513: X/delta/Bp/Cp in RASTER (node)
// order, 4 nodes per 1024-thread block -- depends only on feats, so it runs
// CONCURRENTLY with the 2 struct blocks (struct latency hides it). rs is
// recomputed locally (reduction-order fp diff vs struct's copy ~1e-7, harmless).
// k_scan gathers via bfs_s[i].
__device__ __forceinline__ void edge_uv(int e, int& u, int& v){
  if (e < 1953){
    int i = e / 63; int k = e - i * 63;
    if (k < 62){ int j = k >> 1; u = i * 32 + j; v = (k & 1) ? u + 32 : u + 1; }
    else { u = i * 32 + 31; v = u + 32; }
  } else { u = 31 * 32 + (e - 1953); v = u + 1; }
}

__global__ __launch_bounds__(1024) void k_sx(float* __restrict__ ws)
{
  __shared__ float s_ninv[1024];
  __shared__ float s_w[NEDGE];
  __shared__ float s_r[1024];
  __shared__ int   s_comp[1024];
  __shared__ int   s_link[1024];
  __shared__ int   s_link2[1024];
  __shared__ unsigned long long s_best[1024];
  __shared__ unsigned char  s_mst[NEDGE];
  __shared__ unsigned short s_adj[1024 * 4];
  __shared__ unsigned char  s_deg[1024];
  __shared__ unsigned short s_bfs[1024];
  __shared__ short          s_parof[1024];
  __shared__ unsigned short s_o2b[1024];
  __shared__ unsigned short s_cur[1024];
  __shared__ unsigned short s_nxt[1024];
  __shared__ unsigned short s_off[1025];
  __shared__ unsigned short s_loff2[1026];
  __shared__ unsigned long long s_rootkey;
  __shared__ int s_ncomp, s_cursz, s_bfscnt, s_nextsz, s_nlvl;

  int tid = threadIdx.x;

  if (blockIdx.x >= 2){
    // ---- raster xdelta branch: 4 nodes per block, reuses s_ninv as xs, s_w as scratch
    int gi = (int)(blockIdx.x - 2) * 4 + (tid >> 8);   // 0..2047
    int b2 = gi >> 10, node = gi & 1023;
    int df = tid & 255;
    int wg = tid >> 8;                                  // node group 0..3
    float f = ws[O_FEATS + ((size_t)(b2 * 1024 + node)) * 256 + df];
    // rs = sigmoid(dot(gproj, feats)/16), reduced within the 4-wave node group
    float v = f * ws[O_GPROJ + b2 * 256 + df];
    v += __shfl_xor(v, 1);  v += __shfl_xor(v, 2);  v += __shfl_xor(v, 4);
    v += __shfl_xor(v, 8);  v += __shfl_xor(v, 16); v += __shfl_xor(v, 32);
    if ((tid & 63) == 0) s_w[tid >> 6] = v;             // 16 wave partials
    __syncthreads();
    float gdot = s_w[wg * 4] + s_w[wg * 4 + 1] + s_w[wg * 4 + 2] + s_w[wg * 4 + 3];
    float rs = 1.f / (1.f + expf(-gdot * (1.f / 16.f)));
    float xv = f + rs * ws[O_GPRIM + b2 * 256 + df];
    s_ninv[tid] = xv;                                   // xs[wg][df]
    ws[O_X + (size_t)gi * 256 + df] = xv;
    __syncthreads();
    {
      const float* WT = ws + O_WDW;
      const float* xg = s_ninv + wg * 256;
      float z = ws[O_WDB + df];
      #pragma unroll 8
      for (int k = 0; k < 256; k++)
        z += WT[(size_t)k * 256 + df] * xg[k];
      float sp = fmaxf(z, 0.f) + log1pf(expf(-fabsf(z)));
      ws[O_DELTA + (size_t)gi * 256 + df] = sp * (1.f + 2.f * rs);
    }
    if (df < 32){
      int s2 = df & 15;
      const float* WT = ws + ((df < 16) ? O_BWO : O_CWO);   // [k][s]
      const float* xg = s_ninv + wg * 256;
      float a = ws[((df < 16) ? O_BBO : O_CBO) + s2];
      #pragma unroll 8
      for (int k = 0; k < 256; k++) a += WT[k * 16 + s2] * xg[k];
      ws[((df < 16) ? O_BP : O_CP) + (size_t)gi * 16 + s2] = a;
    }
    return;
  }

  // ---- structure branch (blocks 0,1) ----
  int b = blockIdx.x;
  const float* feats = ws + O_FEATS + (size_t)b * NP * DFEAT;

  // norms + fused r_sem + defensive init
  {
    const float4* f4 = (const float4*)(feats + (size_t)tid * 256);
    const float4* g4 = (const float4*)(ws + O_GPROJ + b * 256);
    float d = 0.f, gdot = 0.f;
    for (int k = 0; k < 64; k++){
      float4 q = f4[k]; float4 g = g4[k];
      d += q.x*q.x + q.y*q.y + q.z*q.z + q.w*q.w;
      gdot += q.x*g.x + q.y*g.y + q.z*g.z + q.w*g.w;
    }
    s_ninv[tid] = 1.f / fmaxf(sqrtf(d), 1e-12f);
    float r = 1.f / (1.f + expf(-gdot * (1.f / 16.f)));
    s_r[tid] = r;
    ws[O_RSEM + b * NP + tid] = r;
    s_comp[tid] = tid;
    s_deg[tid] = 0;
    s_bfs[tid] = (unsigned short)tid;
    s_o2b[tid] = (unsigned short)tid;
    s_parof[tid] = -1;
  }
  for (int e = tid; e < NEDGE; e += 1024) s_mst[e] = 0;
  __syncthreads();

  // edge weights
  for (int e = tid; e < NEDGE; e += 1024){
    int u, v; edge_uv(e, u, v);
    const float4* fu = (const float4*)(feats + (size_t)u * 256);
    const float4* fv = (const float4*)(feats + (size_t)v * 256);
    float d = 0.f;
    for (int k = 0; k < 64; k++){ float4 a = fu[k], c = fv[k]; d += a.x*c.x + a.y*c.y + a.z*c.z + a.w*c.w; }
    float cosv = d * s_ninv[u] * s_ninv[v];
    s_w[e] = (1.f - s_r[u]) * (1.f - s_r[v]) * (-cosv) + 1e-6f;
  }
  __syncthreads();

  // Boruvka rounds (barrier-light root chase)
  for (int round = 0; round < 12; round++){
    s_best[tid] = ~0ull;
    __syncthreads();
    for (int e = tid; e < NEDGE; e += 1024){
      int u, v; edge_uv(e, u, v);
      int cu = s_comp[u], cv = s_comp[v];
      if (cu != cv){
        unsigned long long key = (((unsigned long long)f2sort(s_w[e])) << 32) | (unsigned int)e;
        atomicMin(&s_best[cu], key);
        atomicMin(&s_best[cv], key);
      }
    }
    __syncthreads();
    int l = tid;
    if (s_comp[tid] == tid && s_best[tid] != ~0ull){
      int e = (int)(s_best[tid] & 0xffffffffu);
      int u, v; edge_uv(e, u, v);
      s_mst[e] = 1;
      int cu = s_comp[u], cv = s_comp[v];
      l = (cu == tid) ? cv : cu;
    }
    s_link[tid] = l;
    __syncthreads();
    if (l != tid && s_link[l] == tid && tid < l) s_link[tid] = tid; // break 2-cycles
    __syncthreads();
    {
      int x = tid;
      int p = s_link[x];
      while (p != x){ x = p; p = s_link[x]; }
      s_link2[tid] = x;
    }
    __syncthreads();
    s_comp[tid] = s_link2[s_comp[tid]];
    if (tid == 0) s_ncomp = 0;
    __syncthreads();
    if (s_comp[tid] == tid) atomicAdd(&s_ncomp, 1);
    __syncthreads();
    if (s_ncomp == 1) break;
    __syncthreads();
  }
  __syncthreads();

  // weight-ordered adjacency
  {
    int v = tid; int i = v >> 5, j = v & 31;
    float wloc[4]; int nloc[4]; int d = 0;
    if (j > 0){ int e = (i < 31) ? (i * 63 + 2 * (j - 1)) : (1953 + (j - 1));
      if (s_mst[e]){ wloc[d] = s_w[e]; nloc[d] = v - 1; d++; } }
    if (j < 31){ int e = (i < 31) ? (i * 63 + 2 * j) : (1953 + j);
      if (s_mst[e]){ wloc[d] = s_w[e]; nloc[d] = v + 1; d++; } }
    if (i > 0){ int e = (i - 1) * 63 + ((j < 31) ? (2 * j + 1) : 62);
      if (s_mst[e]){ wloc[d] = s_w[e]; nloc[d] = v - 32; d++; } }
    if (i < 31){ int e = i * 63 + ((j < 31) ? (2 * j + 1) : 62);
      if (s_mst[e]){ wloc[d] = s_w[e]; nloc[d] = v + 32; d++; } }
    for (int a = 1; a < d; a++){
      float wv = wloc[a]; int nv = nloc[a]; int c = a - 1;
      while (c >= 0 && wloc[c] > wv){ wloc[c+1] = wloc[c]; nloc[c+1] = nloc[c]; c--; }
      wloc[c+1] = wv; nloc[c+1] = nv;
    }
    s_deg[v] = (unsigned char)d;
    for (int a = 0; a < d; a++) s_adj[v * 4 + a] = (unsigned short)nloc[a];
  }
  // root = argmax r (first index on ties)
  if (tid == 0) s_rootkey = 0ull;
  __syncthreads();
  {
    unsigned long long key = (((unsigned long long)f2sort(s_r[tid])) << 32) | (unsigned int)(1023 - tid);
    atomicMax(&s_rootkey, key);
  }
  __syncthreads();
  int root = 1023 - (int)(s_rootkey & 0xffffffffu);

  // level-parallel tree BFS
  if (tid == 0){
    s_bfs[0] = (unsigned short)root; s_o2b[root] = 0; s_parof[root] = -1;
    s_cur[0] = (unsigned short)root; s_cursz = 1; s_bfscnt = 1; s_nlvl = 0;
  }
  __syncthreads();
  for (int lev = 0; lev < 1024; lev++){
    int csz = s_cursz;
    if (csz <= 0) break;
    if (tid < 64){
      int runbase = 0;
      for (int t0 = 0; t0 < csz; t0 += 64){
        int t = t0 + tid;
        int cnt = 0;
        if (t < csz){
          int n = s_cur[t];
          cnt = (int)s_deg[n] - (s_parof[n] >= 0 ? 1 : 0);
        }
        int v = cnt;
        #pragma unroll
        for (int off = 1; off < 64; off <<= 1){
          int u2 = __shfl_up(v, off);
          if (tid >= off) v += u2;
        }
        if (t < csz) s_off[t] = (unsigned short)(runbase + v - cnt);
        runbase += __shfl(v, 63);
      }
      if (tid == 0){
        if (s_nlvl < 1025){ s_loff2[s_nlvl] = (unsigned short)(s_bfscnt - csz); }
        s_nlvl++;
        s_nextsz = runbase;
      }
    }
    __syncthreads();
    if (tid < csz){
      int n = s_cur[tid]; int base = s_off[tid]; int k = 0;
      int pn = s_parof[n]; int dg = s_deg[n];
      for (int a = 0; a < dg; a++){
        int c = s_adj[n * 4 + a];
        if (c == pn) continue;
        s_parof[c] = (short)n;
        if (base + k < 1024) s_nxt[base + k] = (unsigned short)c;
        int pos = s_bfscnt + base + k;
        if (pos < 1024){
          s_bfs[pos] = (unsigned short)c;
          s_o2b[c] = (unsigned short)pos;
        }
        k++;
      }
    }
    __syncthreads();
    if (tid == 0){ s_bfscnt += s_nextsz; s_cursz = (s_nextsz > 1024) ? 1024 : s_nextsz; }
    __syncthreads();
    if (tid < s_cursz) s_cur[tid] = s_nxt[tid];
    __syncthreads();
  }
  __syncthreads();

  int* BFSo = (int*)(ws + O_BFS);
  int* PARo = (int*)(ws + O_PAR);
  {
    int node = s_bfs[tid] & 1023;
    BFSo[b * 1024 + tid] = node;
    int p = s_parof[node];
    PARo[b * 1024 + tid] = (p < 0) ? -1 : (int)(s_o2b[p] & 1023);
  }
  {
    int* LVLo = (int*)(ws + O_LVL) + b * 1040;
    int nl = s_nlvl; if (nl > 1024) nl = 1024;
    if (tid == 0){ LVLo[0] = nl; LVLo[1 + nl] = NP; }
    if (tid < nl) LVLo[1 + tid] = (int)s_loff2[tid];
  }
}

// ---------------- K5: tree scan, LEVEL-PARALLEL, 256 threads -------------------------
// Gathers X/DELTA/BP/CP from RASTER order via bfs_s[i].
__global__ __launch_bounds__(256) void k_scan(float* __restrict__ ws)
{
  __shared__ float h[NP * DSTATE];   // 64 KB: h[pos][s]
  __shared__ float xs[NP];
  __shared__ float ds[NP];
  __shared__ int   par_s[NP];
  __shared__ int   bfs_s[NP];
  int blk = blockIdx.x; int b = blk >> 8, f = blk & 255;
  int tid = threadIdx.x;
  int g = tid >> 4, s = tid & 15;
  const int* PARo = (const int*)(ws + O_PAR);
  const int* BFSo = (const int*)(ws + O_BFS);
  const int* LVLo = (const int*)(ws + O_LVL) + b * 1040;
  for (int i = tid; i < NP; i += 256){
    int node = BFSo[b * NP + i] & 1023;
    bfs_s[i] = node;
    par_s[i] = PARo[b * NP + i];
    xs[i] = ws[O_X     + ((size_t)(b * NP + node)) * DFEAT + f];
    ds[i] = ws[O_DELTA + ((size_t)(b * NP + node)) * DFEAT + f];
  }
  __syncthreads();

  int nlvl = LVLo[0];
  bool degen = (nlvl < 1 || nlvl > NP);
  if (degen) nlvl = NP;               // fallback: one node per level == serial order

  float Aln = ws[O_AF + f * 16 + s];
  float Dv  = ws[O_DD + f];
  const float* Bp = ws + O_BP + (size_t)b * NP * DSTATE;
  const float* Cp = ws + O_CP + (size_t)b * NP * DSTATE;
  float* Yr = ws + O_YR + (size_t)b * NP * DFEAT;

  for (int l = 0; l < nlvl; l++){
    int o0, o1;
    if (degen){ o0 = l; o1 = l + 1; }
    else {
      o0 = LVLo[1 + l]; o1 = LVLo[2 + l];
      o0 = (o0 < 0) ? 0 : ((o0 > NP) ? NP : o0);
      o1 = (o1 < o0) ? o0 : ((o1 > NP) ? NP : o1);
    }
    for (int i = o0 + g; i < o1; i += 16){
      int p = par_s[i];
      int node = bfs_s[i];
      float d = ds[i], x = xs[i];
      float hp = (p >= 0 && p < i) ? h[p * 16 + s] : 0.f;
      float hn = expf(d * Aln) * hp + d * Bp[node * 16 + s] * x;
      h[i * 16 + s] = hn;
      float t = hn * Cp[node * 16 + s];
      t += __shfl_xor(t, 1); t += __shfl_xor(t, 2);
      t += __shfl_xor(t, 4); t += __shfl_xor(t, 8);
      if (s == 0) Yr[(size_t)node * DFEAT + f] = t + Dv * x;
    }
    __syncthreads();   // orders level l writes vs l+1 reads
  }
}

// ---------------- K6: out GEMM (k-major coalesced) + LayerNorm -> out dtype ----------
__global__ __launch_bounds__(256) void k_outln(const float* __restrict__ ws,
                                               void* __restrict__ out)
{
  __shared__ float yl[256];
  __shared__ float red[8];
  const int F = ((const int*)(ws + O_FLAG))[0];
  int blk = blockIdx.x; int b = blk >> 10, p = blk & 1023; int df = threadIdx.x;
  yl[df] = ws[O_YR + ((size_t)(b * 1024 + p)) * 256 + df];
  __syncthreads();
  const float* OT = ws + O_OW;   // [k][df]
  float a = ws[O_OB + df];
  #pragma unroll 8
  for (int k = 0; k < 256; k++)
    a += OT[(size_t)k * 256 + df] * yl[k];
  int lane = df & 63, wid = df >> 6;
  float t = a;
  t += __shfl_xor(t, 1); t += __shfl_xor(t, 2);  t += __shfl_xor(t, 4);
  t += __shfl_xor(t, 8); t += __shfl_xor(t, 16); t += __shfl_xor(t, 32);
  if (lane == 0) red[wid] = t;
  __syncthreads();
  float mu = (red[0] + red[1] + red[2] + red[3]) * (1.f / 256.f);
  float dv = a - mu;
  float t2 = dv * dv;
  t2 += __shfl_xor(t2, 1); t2 += __shfl_xor(t2, 2);  t2 += __shfl_xor(t2, 4);
  t2 += __shfl_xor(t2, 8); t2 += __shfl_xor(t2, 16); t2 += __shfl_xor(t2, 32);
  if (lane == 0) red[4 + wid] = t2;
  __syncthreads();
  float var = (red[4] + red[5] + red[6] + red[7]) * (1.f / 256.f);
  float o = ws[O_LNG + df] * dv / sqrtf(var + 1e-5f) + ws[O_LNB + df];
  size_t idx = ((size_t)(b * 1024 + p)) * 256 + df;
  if (F) ((ushortb*)out)[idx] = f2bf(o);
  else   ((float*)out)[idx]   = o;
}

// ---------------- launch ----------------
extern "C" void kernel_launch(void* const* d_in, const int* in_sizes, int n_in,
                              void* d_out, int out_size, void* d_ws, size_t ws_size,
                              hipStream_t stream)
{
  (void)in_sizes; (void)n_in; (void)out_size; (void)ws_size;
  const void* img   = d_in[0];
  const void* lang  = d_in[1];
  const void* c1w   = d_in[2];
  const void* c1b   = d_in[3];
  const void* c2w   = d_in[4];
  const void* c2b   = d_in[5];
  const void* fcw   = d_in[6];
  const void* fcb   = d_in[7];
  const void* wgate = d_in[8];
  const void* wgp   = d_in[9];
  const void* alog  = d_in[10];
  const void* dvec  = d_in[11];
  const void* bw    = d_in[12];
  const void* bb    = d_in[13];
  const void* cw    = d_in[14];
  const void* cb    = d_in[15];
  const void* wdw   = d_in[16];
  const void* wdb   = d_in[17];
  const void* ow    = d_in[18];
  const void* ob    = d_in[19];
  const void* lng   = d_in[20];
  const void* lnb   = d_in[21];
  float* ws = (float*)d_ws;

  k_sniff<<<1, 256, 0, stream>>>(img, ws);
  k_convert<<<990 + 2048 + 256, 256, 0, stream>>>(c1w, c1b, c2w, c2b, fcw, fcb, alog, dvec,
                                                  bw, bb, cw, cb, wdw, wdb, ow, ob, lng, lnb,
                                                  lang, wgate, wgp, ws);
  k_patch<<<2048, 512, 0, stream>>>(img, ws, ws + O_FEATS);
  k_sx<<<2 + 512, 1024, 0, stream>>>(ws);
  k_scan<<<NB * DFEAT, 256, 0, stream>>>(ws);
  k_outln<<<2048, 256, 0, stream>>>(ws, d_out);
}

// Round 10
// 843.131 us; speedup vs baseline: 1.0151x; 1.0151x over previous
//
#include <hip/hip_runtime.h>
#include <cstddef>
#include <cstdint>

// ---------------- constants ----------------
#define NB    2
#define NP    1024    // patches per image
#define DFEAT 256
#define DSTATE 16
#define NEDGE 1984    // grid edges: 31*63 + 31

typedef unsigned short ushortb;

// MFMA fragment types (gfx950 32x32x16 bf16)
typedef float fx16 __attribute__((ext_vector_type(16)));
typedef short s16x8 __attribute__((ext_vector_type(8)));

// ---------------- helpers ----------------
__device__ __forceinline__ float bf2f(unsigned short u){
  union { unsigned int i; float f; } c; c.i = ((unsigned int)u) << 16; return c.f;
}
__device__ __forceinline__ unsigned short f2bf(float f){
  union { float f; unsigned int i; } c; c.f = f;
  unsigned int u = c.i;
  unsigned int r = (u + 0x7fffu + ((u >> 16) & 1u)) >> 16;
  return (unsigned short)r;
}
// dtype-generic input load: isbf ? bf16[i] : fp32[i]
__device__ __forceinline__ float ldin(const void* p, size_t i, int isbf){
  return isbf ? bf2f(((const ushortb*)p)[i]) : ((const float*)p)[i];
}
__device__ __forceinline__ float gelu_f(float x){
  return 0.5f * x * (1.0f + erff(x * 0.70710678118654752f));
}
__device__ __forceinline__ unsigned int f2sort(float f){
  union { float f; unsigned int i; } c; c.f = f;
  return (c.i & 0x80000000u) ? ~c.i : (c.i | 0x80000000u);
}

// ---------------- ws layout (float element offsets) ----------------
constexpr size_t AL(size_t x){ return (x + 63) & ~(size_t)63; }
constexpr size_t O_W1    = 0;                       // 1728  conv1 w fp32
constexpr size_t O_B1    = AL(O_W1 + 1728);         // 64
constexpr size_t O_W2    = AL(O_B1 + 64);           // 73728 floats = 147456 bf16, FRAGMENT-MAJOR
                                                    //   sg = c*18 + tap*2 + ksub (c = 32-ic chunk)
constexpr size_t O_B2    = AL(O_W2 + 73728);        // 128
constexpr size_t O_FCW   = AL(O_B2 + 128);          // 32768 [df][128]
constexpr size_t O_FCB   = AL(O_FCW + 32768);       // 256
constexpr size_t O_WDW   = AL(O_FCB + 256);         // 65536 TRANSPOSED [k][df]
constexpr size_t O_WDB   = AL(O_WDW + 65536);       // 256
constexpr size_t O_BWO   = AL(O_WDB + 256);         // 4096 TRANSPOSED [k][s]
constexpr size_t O_BBO   = AL(O_BWO + 4096);        // 16
constexpr size_t O_CWO   = AL(O_BBO + 16);          // 4096 TRANSPOSED [k][s]
constexpr size_t O_CBO   = AL(O_CWO + 4096);        // 16
constexpr size_t O_OW    = AL(O_CBO + 16);          // 65536 TRANSPOSED [k][df]
constexpr size_t O_OB    = AL(O_OW + 65536);        // 256
constexpr size_t O_AF    = AL(O_OB + 256);          // 4096  A = -exp(A_log), [f][s]
constexpr size_t O_DD    = AL(O_AF + 4096);         // 256
constexpr size_t O_LNG   = AL(O_DD + 256);          // 256
constexpr size_t O_LNB   = AL(O_LNG + 256);         // 256
constexpr size_t O_FEATS = AL(O_LNB + 256);         // 2*1024*256
constexpr size_t O_GPROJ = AL(O_FEATS + (size_t)NB*NP*DFEAT); // 512
constexpr size_t O_GPRIM = AL(O_GPROJ + NB*DFEAT);  // 512
constexpr size_t O_RSEM  = AL(O_GPRIM + NB*DFEAT);  // 2048
constexpr size_t O_BFS   = AL(O_RSEM + NB*NP);      // 2048 (int)
constexpr size_t O_PAR   = AL(O_BFS + NB*NP);       // 2048 (int)
constexpr size_t O_X     = AL(O_PAR + NB*NP);       // 2*1024*256 RASTER (node) order
constexpr size_t O_DELTA = AL(O_X + (size_t)NB*NP*DFEAT);     // RASTER order
constexpr size_t O_BP    = AL(O_DELTA + (size_t)NB*NP*DFEAT); // 2*1024*16 RASTER
constexpr size_t O_CP    = AL(O_BP + NB*NP*DSTATE);           // RASTER
constexpr size_t O_YR    = AL(O_CP + NB*NP*DSTATE); // 2*1024*256
constexpr size_t O_FLAG  = AL(O_YR + (size_t)NB*NP*DFEAT);    // 1 int: is-bf16 flag
constexpr size_t O_LVL   = AL(O_FLAG + 64);         // NB*1040 ints: [nlvl, loff[0..nlvl]]

// ---------------- K-1: sniff input dtype (bf16 vs fp32) from images buffer -----------
__global__ __launch_bounds__(256) void k_sniff(const void* img, float* ws)
{
  __shared__ int cnt;
  int tid = threadIdx.x;
  if (tid == 0) cnt = 0;
  __syncthreads();
  const ushortb* u = (const ushortb*)img;
  int local = 0;
  for (int k = 0; k < 16; k++){
    unsigned short v = u[tid * 16 + k];
    if (v == 0 || v == 0x8000u){ local++; continue; }
    float f = fabsf(bf2f(v));
    if (f >= 1e-8f && f <= 64.f) local++;    // plausible N(0,1) bf16
  }
  atomicAdd(&cnt, local);
  __syncthreads();
  if (tid == 0) ((int*)(ws + O_FLAG))[0] = (cnt >= 3900) ? 1 : 0;  // >=95% plausible
}

// ---------------- K0: convert weights + zero YR + g_proj/g_prime (all fused) ---------
// blocks [0,990): weight convert; [990,3038): YR zero; [3038,3294): gmm rows.
__global__ __launch_bounds__(256) void k_convert(const void* c1w, const void* c1b, const void* c2w,
                          const void* c2b, const void* fcw, const void* fcb,
                          const void* alog, const void* dvec,
                          const void* bw, const void* bb, const void* cw, const void* cb,
                          const void* wdw, const void* wdb,
                          const void* ow, const void* ob,
                          const void* lng, const void* lnb,
                          const void* lang, const void* wgate, const void* wgp,
                          float* ws)
{
  const int F = ((const int*)(ws + O_FLAG))[0];
  if (blockIdx.x >= 3038){  // gmm branch: wave-per-row coalesced dual GEMV
    int row = (blockIdx.x - 3038) * 4 + (threadIdx.x >> 6);
    int lane = threadIdx.x & 63;
    int mat = row >> 9;
    int b   = (row >> 8) & 1;
    int df  = row & 255;
    const void* W = mat ? wgp : wgate;
    float s = 0.f;
    for (int k = lane; k < 896; k += 64)
      s += ldin(lang, (size_t)b * 896 + k, F) * ldin(W, (size_t)df * 896 + k, F);
    s += __shfl_xor(s, 1);  s += __shfl_xor(s, 2);  s += __shfl_xor(s, 4);
    s += __shfl_xor(s, 8);  s += __shfl_xor(s, 16); s += __shfl_xor(s, 32);
    if (lane == 0) ws[(mat ? O_GPRIM : O_GPROJ) + b * 256 + df] = s;
    return;
  }
  if (blockIdx.x >= 990){   // init branch: zero YR
    size_t i2 = (size_t)(blockIdx.x - 990) * 256 + threadIdx.x;
    if (i2 < (size_t)NB * NP * DFEAT) ws[O_YR + i2] = 0.f;
    return;
  }
  int i = blockIdx.x * 256 + threadIdx.x;
  if (i < 1728){ ws[O_W1 + i] = ldin(c1w, i, F); return; } i -= 1728;
  if (i < 64){ ws[O_B1 + i] = ldin(c1b, i, F); return; } i -= 64;
  if (i < 73728){
    // fragment-major bf16-split conv2 weights for 32x32x16 MFMA.
    // sg = c*18 + tap*2 + ksub (c = 32-ic chunk); lane ln holds oc = nt*32+(ln&31),
    // ic = c*32 + ksub*16 + (ln>>5)*8 + e.
    int sg = i >> 11;           // 0..35
    int r = i & 2047;
    int nt = r >> 9;
    int r2 = r & 511;           // ln*8 + e
    int ln = r2 >> 3, e = r2 & 7;
    int c  = sg / 18, s = sg - c * 18;
    int tap = s >> 1, ksub = s & 1;
    int oc = nt * 32 + (ln & 31);
    int ic = c * 32 + ksub * 16 + (ln >> 5) * 8 + e;
    float v = ldin(c2w, (size_t)(oc * 64 + ic) * 9 + tap, F);
    ushortb hi = f2bf(v);
    float lo = v - bf2f(hi);
    ushortb* WB = (ushortb*)(ws + O_W2);
    size_t cb = ((size_t)(sg * 4 + nt)) * 2;
    WB[cb * 512 + r2]       = hi;         // plane 0
    WB[(cb + 1) * 512 + r2] = f2bf(lo);   // plane 1
    return;
  } i -= 73728;
  if (i < 128){ ws[O_B2 + i] = ldin(c2b, i, F); return; } i -= 128;
  if (i < 32768){ ws[O_FCW + i] = ldin(fcw, i, F); return; } i -= 32768;
  if (i < 256){ ws[O_FCB + i] = ldin(fcb, i, F); return; } i -= 256;
  if (i < 65536){  // WDW transposed: dst[k*256+df] = src[df*256+k]
    int k = i >> 8, df = i & 255;
    ws[O_WDW + i] = ldin(wdw, (size_t)df * 256 + k, F); return;
  } i -= 65536;
  if (i < 256){ ws[O_WDB + i] = ldin(wdb, i, F); return; } i -= 256;
  if (i < 4096){   // B_w transposed: dst[k*16+s] = src[s*256+k]
    int k = i >> 4, s = i & 15;
    ws[O_BWO + i] = ldin(bw, (size_t)s * 256 + k, F); return;
  } i -= 4096;
  if (i < 16){ ws[O_BBO + i] = ldin(bb, i, F); return; } i -= 16;
  if (i < 4096){   // C_w transposed
    int k = i >> 4, s = i & 15;
    ws[O_CWO + i] = ldin(cw, (size_t)s * 256 + k, F); return;
  } i -= 4096;
  if (i < 16){ ws[O_CBO + i] = ldin(cb, i, F); return; } i -= 16;
  if (i < 65536){  // out_w transposed: dst[k*256+df] = src[df*256+k]
    int k = i >> 8, df = i & 255;
    ws[O_OW + i] = ldin(ow, (size_t)df * 256 + k, F); return;
  } i -= 65536;
  if (i < 256){ ws[O_OB + i] = ldin(ob, i, F); return; } i -= 256;
  if (i < 4096){ ws[O_AF + i] = -expf(ldin(alog, i, F)); return; } i -= 4096;
  if (i < 256){ ws[O_DD + i] = ldin(dvec, i, F); return; } i -= 256;
  if (i < 256){ ws[O_LNG + i] = ldin(lng, i, F); return; } i -= 256;
  if (i < 256){ ws[O_LNB + i] = ldin(lnb, i, F); }
}

// ---------------- K1: per-patch conv1 + MFMA conv2 (bf16 3-split, M-halves) ----------
// R9 = R8 with the K-loop restored to sg-SEQUENTIAL order (chunk-major): R8's
// tap-major order ping-ponged +-144KB through the fragment-major B buffer each
// step pair, breaking L2 streaming (MfmaUtil 27.5 -> 25.5, dur +32us). Sequential
// sg also makes per-acc-element summation order IDENTICAL to R7 -> bitwise-same
// feats. conv1 stays at R8's 1.125x (M-half halo scheme).
__global__ __launch_bounds__(512, 4) void k_patch(const void* __restrict__ img,
                                                  const float* __restrict__ ws,
                                                  float* __restrict__ feats)
{
  __shared__ __align__(16) ushortb Abuf[2 * 11520];  // hi [0], lo [11520]: [10][18][64]
  __shared__ float timg[768];      // [3 c][256 px]
  __shared__ float pool8[512];     // [wv][2 nt local][32 oc]
  __shared__ float pm[128];        // pooled mean
  const int F = ((const int*)(ws + O_FLAG))[0];
  const float* W1 = ws + O_W1;  const float* B1 = ws + O_B1;
  const float* FCW = ws + O_FCW; const float* FCB = ws + O_FCB;
  const s16x8* BF = (const s16x8*)(ws + O_W2);   // fragment-major B

  int blk = blockIdx.x; int b = blk >> 10; int pidx = blk & 1023;
  int ph = pidx >> 5, pw = pidx & 31;
  int tid = threadIdx.x;
  uint4 z4 = make_uint4(0u, 0u, 0u, 0u);

  // stage input tile (16x16x3) into LDS
  if (tid < 256){
    int y = tid >> 4, x = tid & 15;
    #pragma unroll
    for (int c = 0; c < 3; c++)
      timg[c * 256 + tid] =
        ldin(img, (((size_t)b * 3 + c) * 512 + (ph * 16 + y)) * 512 + (pw * 16 + x), F);
  }
  // zero column pads (gc = 0, 17) for all 10 rows, both planes (never overwritten)
  for (int z = tid; z < 320; z += 512){
    int plane = z / 160; int z2 = z - plane * 160;   // 160 = 10 rows * 2 cols * 8 q
    int cell = z2 >> 3, q = z2 & 7;
    int lr = cell >> 1; int gc = (cell & 1) ? 17 : 0;
    *(uint4*)&Abuf[plane * 11520 + ((lr * 18 + gc) << 6) + (q << 3)] = z4;
  }
  __syncthreads();

  int wv = tid >> 6, ln = tid & 63;
  int l31 = ln & 31, lhi = ln >> 5;
  int xcol = ln & 15, yrow = l31 >> 4;
  int mt = wv >> 1, ng = wv & 1;

  float psum0 = 0.f, psum1 = 0.f;   // pooled partials (lane-local, across halves)

  for (int h = 0; h < 2; h++){
    // zero this half's pad row (lr = h?9:0, gc 1..16, both planes)
    {
      int pr = h ? 9 : 0;
      for (int z = tid; z < 256; z += 512){
        int plane = z >> 7; int z2 = z & 127;
        int gc = 1 + (z2 >> 3); int q = z2 & 7;
        *(uint4*)&Abuf[plane * 11520 + ((pr * 18 + gc) << 6) + (q << 3)] = z4;
      }
    }
    // conv1: 9 image rows (h ? 7..15 : 0..8); 1152 units of (px 0..143, 8-oc group)
    for (int u = tid; u < 1152; u += 512){
      int og = u / 144; int px = u - og * 144;
      int r9 = px >> 4, col = px & 15;
      int ir = h ? (7 + r9) : r9;
      float pin[27];
      #pragma unroll
      for (int cc = 0; cc < 3; cc++)
        #pragma unroll
        for (int dy = 0; dy < 3; dy++)
          #pragma unroll
          for (int dx = 0; dx < 3; dx++){
            int y = ir + dy - 1, x = col + dx - 1;
            bool ok = (y >= 0 && y < 16 && x >= 0 && x < 16);
            pin[cc * 9 + dy * 3 + dx] = ok ? timg[cc * 256 + y * 16 + x] : 0.f;
          }
      int oc0 = og * 8;
      float av[8];
      #pragma unroll
      for (int o = 0; o < 8; o++){
        float a = B1[oc0 + o];
        #pragma unroll
        for (int t = 0; t < 27; t++) a += W1[(oc0 + o) * 27 + t] * pin[t];
        av[o] = gelu_f(a);
      }
      unsigned int hp[4], lp[4];
      #pragma unroll
      for (int q = 0; q < 4; q++){
        float v0 = av[2 * q], v1 = av[2 * q + 1];
        ushortb h0 = f2bf(v0), h1 = f2bf(v1);
        float l0 = v0 - bf2f(h0), l1 = v1 - bf2f(h1);
        hp[q] = (unsigned int)h0 | ((unsigned int)h1 << 16);
        lp[q] = (unsigned int)f2bf(l0) | ((unsigned int)f2bf(l1) << 16);
      }
      int lr = h ? r9 : (r9 + 1);
      int gc = col + 1;
      int idx = ((lr * 18 + gc) << 6) + ((og ^ (gc & 7)) << 3);
      *(uint4*)&Abuf[idx] = make_uint4(hp[0], hp[1], hp[2], hp[3]);
      *(uint4*)&Abuf[11520 + idx] = make_uint4(lp[0], lp[1], lp[2], lp[3]);
    }
    __syncthreads();

    // MFMA: full K = 576 in 36 steps, sg-SEQUENTIAL (chunk c outer, tap, ksub)
    // -> B pointer advances by a constant 512 fragments/step (L2 streaming).
    fx16 acc0, acc1;
    #pragma unroll
    for (int r = 0; r < 16; r++){ acc0[r] = 0.f; acc1[r] = 0.f; }
    {
      const s16x8* bq = BF + (size_t)((ng * 2) * 2) * 64 + ln;   // sg=0 base
      for (int sg = 0; sg < 36; sg++){
        int c = (sg >= 18) ? 1 : 0;
        int rem = sg - c * 18;
        int tap = rem >> 1, ksub = rem & 1;
        int dyq = tap / 3, dxq = tap - dyq * 3;
        int lr = 2 * mt + yrow + dyq;           // local padded row 0..9
        int gc = xcol + dxq;                    // padded col 0..17
        int slot = ((c * 2 + ksub) << 1) + lhi; // 8-ic slot 0..7
        int iA = ((lr * 18 + gc) << 6) + ((slot ^ (gc & 7)) << 3);
        s16x8 fa_h = *(const s16x8*)&Abuf[iA];
        s16x8 fa_l = *(const s16x8*)&Abuf[11520 + iA];
        s16x8 fb0h = bq[0];
        s16x8 fb0l = bq[64];
        s16x8 fb1h = bq[128];
        s16x8 fb1l = bq[192];
        acc0 = __builtin_amdgcn_mfma_f32_32x32x16_bf16(fa_h, fb0h, acc0, 0, 0, 0);
        acc1 = __builtin_amdgcn_mfma_f32_32x32x16_bf16(fa_h, fb1h, acc1, 0, 0, 0);
        acc0 = __builtin_amdgcn_mfma_f32_32x32x16_bf16(fa_l, fb0h, acc0, 0, 0, 0);
        acc1 = __builtin_amdgcn_mfma_f32_32x32x16_bf16(fa_l, fb1h, acc1, 0, 0, 0);
        acc0 = __builtin_amdgcn_mfma_f32_32x32x16_bf16(fa_h, fb0l, acc0, 0, 0, 0);
        acc1 = __builtin_amdgcn_mfma_f32_32x32x16_bf16(fa_h, fb1l, acc1, 0, 0, 0);
        bq += 512;                              // next sg (8 fragment-chunks of 64)
      }
    }
    // pool this half's output (bias + gelu), accumulate lane-local
    {
      float bz0 = ws[O_B2 + (ng * 2) * 32 + l31];
      float bz1 = ws[O_B2 + (ng * 2 + 1) * 32 + l31];
      float s0 = 0.f, s1 = 0.f;
      #pragma unroll
      for (int r = 0; r < 16; r++){
        s0 += gelu_f(acc0[r] + bz0);
        s1 += gelu_f(acc1[r] + bz1);
      }
      psum0 += s0; psum1 += s1;
    }
    __syncthreads();   // A dead before next half's conv1 overwrites it
  }

  // fold k-half lanes, write per-wave pool partials: pool8[wv][n][32]
  {
    float s0 = psum0 + __shfl_xor(psum0, 32);
    float s1 = psum1 + __shfl_xor(psum1, 32);
    if (lhi == 0){
      pool8[wv * 64 + l31] = s0;
      pool8[wv * 64 + 32 + l31] = s1;
    }
  }
  __syncthreads();
  if (tid < 128){
    int oc = tid; int nt = oc >> 5; int ngo = nt >> 1; int n = nt & 1; int l = oc & 31;
    float sv = pool8[(0 * 2 + ngo) * 64 + n * 32 + l]
             + pool8[(1 * 2 + ngo) * 64 + n * 32 + l]
             + pool8[(2 * 2 + ngo) * 64 + n * 32 + l]
             + pool8[(3 * 2 + ngo) * 64 + n * 32 + l];
    pm[oc] = sv * (1.f / 256.f);
  }
  __syncthreads();

  // fc 128 -> 256 (threads 0..255)
  if (tid < 256){
    int df = tid;
    float s = FCB[df];
    const float* wrow = FCW + (size_t)df * 128;
    #pragma unroll
    for (int k = 0; k < 128; k += 4)
      s += wrow[k] * pm[k] + wrow[k + 1] * pm[k + 1]
         + wrow[k + 2] * pm[k + 2] + wrow[k + 3] * pm[k + 3];
    feats[((size_t)(b * 1024 + pidx)) * 256 + df] = s;
  }
}

// ---------------- K3: FUSED structure + raster xdelta --------------------------------
// blocks 0,1: MST+BFS (per batch). blocks 2..513: X/delta/Bp/Cp in RASTER (node)
// order, 4 nodes per 1024-thread block -- depends only on feats, so it runs
// CONCURRENTLY with the 2 struct blocks (struct latency hides it). k_scan gathers
// via bfs_s[i].
__device__ __forceinline__ void edge_uv(int e, int& u, int& v){
  if (e < 1953){
    int i = e / 63; int k = e - i * 63;
    if (k < 62){ int j = k >> 1; u = i * 32 + j; v = (k & 1) ? u + 32 : u + 1; }
    else { u = i * 32 + 31; v = u + 32; }
  } else { u = 31 * 32 + (e - 1953); v = u + 1; }
}

__global__ __launch_bounds__(1024) void k_sx(float* __restrict__ ws)
{
  __shared__ float s_ninv[1024];
  __shared__ float s_w[NEDGE];
  __shared__ float s_r[1024];
  __shared__ int   s_comp[1024];
  __shared__ int   s_link[1024];
  __shared__ int   s_link2[1024];
  __shared__ unsigned long long s_best[1024];
  __shared__ unsigned char  s_mst[NEDGE];
  __shared__ unsigned short s_adj[1024 * 4];
  __shared__ unsigned char  s_deg[1024];
  __shared__ unsigned short s_bfs[1024];
  __shared__ short          s_parof[1024];
  __shared__ unsigned short s_o2b[1024];
  __shared__ unsigned short s_cur[1024];
  __shared__ unsigned short s_nxt[1024];
  __shared__ unsigned short s_off[1025];
  __shared__ unsigned short s_loff2[1026];
  __shared__ unsigned long long s_rootkey;
  __shared__ int s_ncomp, s_cursz, s_bfscnt, s_nextsz, s_nlvl;

  int tid = threadIdx.x;

  if (blockIdx.x >= 2){
    // ---- raster xdelta branch: 4 nodes per block, reuses s_ninv as xs, s_w as scratch
    int gi = (int)(blockIdx.x - 2) * 4 + (tid >> 8);   // 0..2047
    int b2 = gi >> 10, node = gi & 1023;
    int df = tid & 255;
    int wg = tid >> 8;                                  // node group 0..3
    float f = ws[O_FEATS + ((size_t)(b2 * 1024 + node)) * 256 + df];
    // rs = sigmoid(dot(gproj, feats)/16), reduced within the 4-wave node group
    float v = f * ws[O_GPROJ + b2 * 256 + df];
    v += __shfl_xor(v, 1);  v += __shfl_xor(v, 2);  v += __shfl_xor(v, 4);
    v += __shfl_xor(v, 8);  v += __shfl_xor(v, 16); v += __shfl_xor(v, 32);
    if ((tid & 63) == 0) s_w[tid >> 6] = v;             // 16 wave partials
    __syncthreads();
    float gdot = s_w[wg * 4] + s_w[wg * 4 + 1] + s_w[wg * 4 + 2] + s_w[wg * 4 + 3];
    float rs = 1.f / (1.f + expf(-gdot * (1.f / 16.f)));
    float xv = f + rs * ws[O_GPRIM + b2 * 256 + df];
    s_ninv[tid] = xv;                                   // xs[wg][df]
    ws[O_X + (size_t)gi * 256 + df] = xv;
    __syncthreads();
    {
      const float* WT = ws + O_WDW;
      const float* xg = s_ninv + wg * 256;
      float z = ws[O_WDB + df];
      #pragma unroll 8
      for (int k = 0; k < 256; k++)
        z += WT[(size_t)k * 256 + df] * xg[k];
      float sp = fmaxf(z, 0.f) + log1pf(expf(-fabsf(z)));
      ws[O_DELTA + (size_t)gi * 256 + df] = sp * (1.f + 2.f * rs);
    }
    if (df < 32){
      int s2 = df & 15;
      const float* WT = ws + ((df < 16) ? O_BWO : O_CWO);   // [k][s]
      const float* xg = s_ninv + wg * 256;
      float a = ws[((df < 16) ? O_BBO : O_CBO) + s2];
      #pragma unroll 8
      for (int k = 0; k < 256; k++) a += WT[k * 16 + s2] * xg[k];
      ws[((df < 16) ? O_BP : O_CP) + (size_t)gi * 16 + s2] = a;
    }
    return;
  }

  // ---- structure branch (blocks 0,1) ----
  int b = blockIdx.x;
  const float* feats = ws + O_FEATS + (size_t)b * NP * DFEAT;

  // norms + fused r_sem + defensive init
  {
    const float4* f4 = (const float4*)(feats + (size_t)tid * 256);
    const float4* g4 = (const float4*)(ws + O_GPROJ + b * 256);
    float d = 0.f, gdot = 0.f;
    for (int k = 0; k < 64; k++){
      float4 q = f4[k]; float4 g = g4[k];
      d += q.x*q.x + q.y*q.y + q.z*q.z + q.w*q.w;
      gdot += q.x*g.x + q.y*g.y + q.z*g.z + q.w*g.w;
    }
    s_ninv[tid] = 1.f / fmaxf(sqrtf(d), 1e-12f);
    float r = 1.f / (1.f + expf(-gdot * (1.f / 16.f)));
    s_r[tid] = r;
    ws[O_RSEM + b * NP + tid] = r;
    s_comp[tid] = tid;
    s_deg[tid] = 0;
    s_bfs[tid] = (unsigned short)tid;
    s_o2b[tid] = (unsigned short)tid;
    s_parof[tid] = -1;
  }
  for (int e = tid; e < NEDGE; e += 1024) s_mst[e] = 0;
  __syncthreads();

  // edge weights
  for (int e = tid; e < NEDGE; e += 1024){
    int u, v; edge_uv(e, u, v);
    const float4* fu = (const float4*)(feats + (size_t)u * 256);
    const float4* fv = (const float4*)(feats + (size_t)v * 256);
    float d = 0.f;
    for (int k = 0; k < 64; k++){ float4 a = fu[k], c = fv[k]; d += a.x*c.x + a.y*c.y + a.z*c.z + a.w*c.w; }
    float cosv = d * s_ninv[u] * s_ninv[v];
    s_w[e] = (1.f - s_r[u]) * (1.f - s_r[v]) * (-cosv) + 1e-6f;
  }
  __syncthreads();

  // Boruvka rounds (barrier-light root chase)
  for (int round = 0; round < 12; round++){
    s_best[tid] = ~0ull;
    __syncthreads();
    for (int e = tid; e < NEDGE; e += 1024){
      int u, v; edge_uv(e, u, v);
      int cu = s_comp[u], cv = s_comp[v];
      if (cu != cv){
        unsigned long long key = (((unsigned long long)f2sort(s_w[e])) << 32) | (unsigned int)e;
        atomicMin(&s_best[cu], key);
        atomicMin(&s_best[cv], key);
      }
    }
    __syncthreads();
    int l = tid;
    if (s_comp[tid] == tid && s_best[tid] != ~0ull){
      int e = (int)(s_best[tid] & 0xffffffffu);
      int u, v; edge_uv(e, u, v);
      s_mst[e] = 1;
      int cu = s_comp[u], cv = s_comp[v];
      l = (cu == tid) ? cv : cu;
    }
    s_link[tid] = l;
    __syncthreads();
    if (l != tid && s_link[l] == tid && tid < l) s_link[tid] = tid; // break 2-cycles
    __syncthreads();
    {
      int x = tid;
      int p = s_link[x];
      while (p != x){ x = p; p = s_link[x]; }
      s_link2[tid] = x;
    }
    __syncthreads();
    s_comp[tid] = s_link2[s_comp[tid]];
    if (tid == 0) s_ncomp = 0;
    __syncthreads();
    if (s_comp[tid] == tid) atomicAdd(&s_ncomp, 1);
    __syncthreads();
    if (s_ncomp == 1) break;
    __syncthreads();
  }
  __syncthreads();

  // weight-ordered adjacency
  {
    int v = tid; int i = v >> 5, j = v & 31;
    float wloc[4]; int nloc[4]; int d = 0;
    if (j > 0){ int e = (i < 31) ? (i * 63 + 2 * (j - 1)) : (1953 + (j - 1));
      if (s_mst[e]){ wloc[d] = s_w[e]; nloc[d] = v - 1; d++; } }
    if (j < 31){ int e = (i < 31) ? (i * 63 + 2 * j) : (1953 + j);
      if (s_mst[e]){ wloc[d] = s_w[e]; nloc[d] = v + 1; d++; } }
    if (i > 0){ int e = (i - 1) * 63 + ((j < 31) ? (2 * j + 1) : 62);
      if (s_mst[e]){ wloc[d] = s_w[e]; nloc[d] = v - 32; d++; } }
    if (i < 31){ int e = i * 63 + ((j < 31) ? (2 * j + 1) : 62);
      if (s_mst[e]){ wloc[d] = s_w[e]; nloc[d] = v + 32; d++; } }
    for (int a = 1; a < d; a++){
      float wv = wloc[a]; int nv = nloc[a]; int c = a - 1;
      while (c >= 0 && wloc[c] > wv){ wloc[c+1] = wloc[c]; nloc[c+1] = nloc[c]; c--; }
      wloc[c+1] = wv; nloc[c+1] = nv;
    }
    s_deg[v] = (unsigned char)d;
    for (int a = 0; a < d; a++) s_adj[v * 4 + a] = (unsigned short)nloc[a];
  }
  // root = argmax r (first index on ties)
  if (tid == 0) s_rootkey = 0ull;
  __syncthreads();
  {
    unsigned long long key = (((unsigned long long)f2sort(s_r[tid])) << 32) | (unsigned int)(1023 - tid);
    atomicMax(&s_rootkey, key);
  }
  __syncthreads();
  int root = 1023 - (int)(s_rootkey & 0xffffffffu);

  // level-parallel tree BFS
  if (tid == 0){
    s_bfs[0] = (unsigned short)root; s_o2b[root] = 0; s_parof[root] = -1;
    s_cur[0] = (unsigned short)root; s_cursz = 1; s_bfscnt = 1; s_nlvl = 0;
  }
  __syncthreads();
  for (int lev = 0; lev < 1024; lev++){
    int csz = s_cursz;
    if (csz <= 0) break;
    if (tid < 64){
      int runbase = 0;
      for (int t0 = 0; t0 < csz; t0 += 64){
        int t = t0 + tid;
        int cnt = 0;
        if (t < csz){
          int n = s_cur[t];
          cnt = (int)s_deg[n] - (s_parof[n] >= 0 ? 1 : 0);
        }
        int v = cnt;
        #pragma unroll
        for (int off = 1; off < 64; off <<= 1){
          int u2 = __shfl_up(v, off);
          if (tid >= off) v += u2;
        }
        if (t < csz) s_off[t] = (unsigned short)(runbase + v - cnt);
        runbase += __shfl(v, 63);
      }
      if (tid == 0){
        if (s_nlvl < 1025){ s_loff2[s_nlvl] = (unsigned short)(s_bfscnt - csz); }
        s_nlvl++;
        s_nextsz = runbase;
      }
    }
    __syncthreads();
    if (tid < csz){
      int n = s_cur[tid]; int base = s_off[tid]; int k = 0;
      int pn = s_parof[n]; int dg = s_deg[n];
      for (int a = 0; a < dg; a++){
        int c = s_adj[n * 4 + a];
        if (c == pn) continue;
        s_parof[c] = (short)n;
        if (base + k < 1024) s_nxt[base + k] = (unsigned short)c;
        int pos = s_bfscnt + base + k;
        if (pos < 1024){
          s_bfs[pos] = (unsigned short)c;
          s_o2b[c] = (unsigned short)pos;
        }
        k++;
      }
    }
    __syncthreads();
    if (tid == 0){ s_bfscnt += s_nextsz; s_cursz = (s_nextsz > 1024) ? 1024 : s_nextsz; }
    __syncthreads();
    if (tid < s_cursz) s_cur[tid] = s_nxt[tid];
    __syncthreads();
  }
  __syncthreads();

  int* BFSo = (int*)(ws + O_BFS);
  int* PARo = (int*)(ws + O_PAR);
  {
    int node = s_bfs[tid] & 1023;
    BFSo[b * 1024 + tid] = node;
    int p = s_parof[node];
    PARo[b * 1024 + tid] = (p < 0) ? -1 : (int)(s_o2b[p] & 1023);
  }
  {
    int* LVLo = (int*)(ws + O_LVL) + b * 1040;
    int nl = s_nlvl; if (nl > 1024) nl = 1024;
    if (tid == 0){ LVLo[0] = nl; LVLo[1 + nl] = NP; }
    if (tid < nl) LVLo[1 + tid] = (int)s_loff2[tid];
  }
}

// ---------------- K5: tree scan, LEVEL-PARALLEL, 256 threads -------------------------
// Gathers X/DELTA/BP/CP from RASTER order via bfs_s[i].
__global__ __launch_bounds__(256) void k_scan(float* __restrict__ ws)
{
  __shared__ float h[NP * DSTATE];   // 64 KB: h[pos][s]
  __shared__ float xs[NP];
  __shared__ float ds[NP];
  __shared__ int   par_s[NP];
  __shared__ int   bfs_s[NP];
  int blk = blockIdx.x; int b = blk >> 8, f = blk & 255;
  int tid = threadIdx.x;
  int g = tid >> 4, s = tid & 15;
  const int* PARo = (const int*)(ws + O_PAR);
  const int* BFSo = (const int*)(ws + O_BFS);
  const int* LVLo = (const int*)(ws + O_LVL) + b * 1040;
  for (int i = tid; i < NP; i += 256){
    int node = BFSo[b * NP + i] & 1023;
    bfs_s[i] = node;
    par_s[i] = PARo[b * NP + i];
    xs[i] = ws[O_X     + ((size_t)(b * NP + node)) * DFEAT + f];
    ds[i] = ws[O_DELTA + ((size_t)(b * NP + node)) * DFEAT + f];
  }
  __syncthreads();

  int nlvl = LVLo[0];
  bool degen = (nlvl < 1 || nlvl > NP);
  if (degen) nlvl = NP;               // fallback: one node per level == serial order

  float Aln = ws[O_AF + f * 16 + s];
  float Dv  = ws[O_DD + f];
  const float* Bp = ws + O_BP + (size_t)b * NP * DSTATE;
  const float* Cp = ws + O_CP + (size_t)b * NP * DSTATE;
  float* Yr = ws + O_YR + (size_t)b * NP * DFEAT;

  for (int l = 0; l < nlvl; l++){
    int o0, o1;
    if (degen){ o0 = l; o1 = l + 1; }
    else {
      o0 = LVLo[1 + l]; o1 = LVLo[2 + l];
      o0 = (o0 < 0) ? 0 : ((o0 > NP) ? NP : o0);
      o1 = (o1 < o0) ? o0 : ((o1 > NP) ? NP : o1);
    }
    for (int i = o0 + g; i < o1; i += 16){
      int p = par_s[i];
      int node = bfs_s[i];
      float d = ds[i], x = xs[i];
      float hp = (p >= 0 && p < i) ? h[p * 16 + s] : 0.f;
      float hn = expf(d * Aln) * hp + d * Bp[node * 16 + s] * x;
      h[i * 16 + s] = hn;
      float t = hn * Cp[node * 16 + s];
      t += __shfl_xor(t, 1); t += __shfl_xor(t, 2);
      t += __shfl_xor(t, 4); t += __shfl_xor(t, 8);
      if (s == 0) Yr[(size_t)node * DFEAT + f] = t + Dv * x;
    }
    __syncthreads();   // orders level l writes vs l+1 reads
  }
}

// ---------------- K6: out GEMM (k-major coalesced) + LayerNorm -> out dtype ----------
__global__ __launch_bounds__(256) void k_outln(const float* __restrict__ ws,
                                               void* __restrict__ out)
{
  __shared__ float yl[256];
  __shared__ float red[8];
  const int F = ((const int*)(ws + O_FLAG))[0];
  int blk = blockIdx.x; int b = blk >> 10, p = blk & 1023; int df = threadIdx.x;
  yl[df] = ws[O_YR + ((size_t)(b * 1024 + p)) * 256 + df];
  __syncthreads();
  const float* OT = ws + O_OW;   // [k][df]
  float a = ws[O_OB + df];
  #pragma unroll 8
  for (int k = 0; k < 256; k++)
    a += OT[(size_t)k * 256 + df] * yl[k];
  int lane = df & 63, wid = df >> 6;
  float t = a;
  t += __shfl_xor(t, 1); t += __shfl_xor(t, 2);  t += __shfl_xor(t, 4);
  t += __shfl_xor(t, 8); t += __shfl_xor(t, 16); t += __shfl_xor(t, 32);
  if (lane == 0) red[wid] = t;
  __syncthreads();
  float mu = (red[0] + red[1] + red[2] + red[3]) * (1.f / 256.f);
  float dv = a - mu;
  float t2 = dv * dv;
  t2 += __shfl_xor(t2, 1); t2 += __shfl_xor(t2, 2);  t2 += __shfl_xor(t2, 4);
  t2 += __shfl_xor(t2, 8); t2 += __shfl_xor(t2, 16); t2 += __shfl_xor(t2, 32);
  if (lane == 0) red[4 + wid] = t2;
  __syncthreads();
  float var = (red[4] + red[5] + red[6] + red[7]) * (1.f / 256.f);
  float o = ws[O_LNG + df] * dv / sqrtf(var + 1e-5f) + ws[O_LNB + df];
  size_t idx = ((size_t)(b * 1024 + p)) * 256 + df;
  if (F) ((ushortb*)out)[idx] = f2bf(o);
  else   ((float*)out)[idx]   = o;
}

// ---------------- launch ----------------
extern "C" void kernel_launch(void* const* d_in, const int* in_sizes, int n_in,
                              void* d_out, int out_size, void* d_ws, size_t ws_size,
                              hipStream_t stream)
{
  (void)in_sizes; (void)n_in; (void)out_size; (void)ws_size;
  const void* img   = d_in[0];
  const void* lang  = d_in[1];
  const void* c1w   = d_in[2];
  const void* c1b   = d_in[3];
  const void* c2w   = d_in[4];
  const void* c2b   = d_in[5];
  const void* fcw   = d_in[6];
  const void* fcb   = d_in[7];
  const void* wgate = d_in[8];
  const void* wgp   = d_in[9];
  const void* alog  = d_in[10];
  const void* dvec  = d_in[11];
  const void* bw    = d_in[12];
  const void* bb    = d_in[13];
  const void* cw    = d_in[14];
  const void* cb    = d_in[15];
  const void* wdw   = d_in[16];
  const void* wdb   = d_in[17];
  const void* ow    = d_in[18];
  const void* ob    = d_in[19];
  const void* lng   = d_in[20];
  const void* lnb   = d_in[21];
  float* ws = (float*)d_ws;

  k_sniff<<<1, 256, 0, stream>>>(img, ws);
  k_convert<<<990 + 2048 + 256, 256, 0, stream>>>(c1w, c1b, c2w, c2b, fcw, fcb, alog, dvec,
                                                  bw, bb, cw, cb, wdw, wdb, ow, ob, lng, lnb,
                                                  lang, wgate, wgp, ws);
  k_patch<<<2048, 512, 0, stream>>>(img, ws, ws + O_FEATS);
  k_sx<<<2 + 512, 1024, 0, stream>>>(ws);
  k_scan<<<NB * DFEAT, 256, 0, stream>>>(ws);
  k_outln<<<2048, 256, 0, stream>>>(ws, d_out);
}